// Round 1
// 105.375 us; speedup vs baseline: 1.0149x; 1.0149x over previous
//
#include <hip/hip_runtime.h>
#include <math.h>

#define NB 2
#define LL 4096
#define HH 1024
#define DD 64
#define CHK 64
#define NCH 64            /* LL/CHK */
#define BLROWS (NB*LL)    /* 8192 */
#define NCHT (NB*NCH)     /* 128 total chunks */
#define GAMMA 0.96875f

typedef _Float16 f16x8 __attribute__((ext_vector_type(8)));
typedef _Float16 f16x4 __attribute__((ext_vector_type(4)));
typedef float    f32x4 __attribute__((ext_vector_type(4)));

#define WCH 12288   /* Wf frag layout: [16 kchunks][12 ct][2 kt][64 lanes][8] */
#define SBS 584     /* Sb row stride (f16), padded for bank spread */

// ---------------------------------------------------------------------------
// Kernel 0: two jobs.
//  blocks 0..95   : W (scaled 2^10) -> single fp16, fragment order (as before)
//  blocks 96..607 : xPos table gen. tab[mat][i2][pos] = (cos*scl, sin*scl),
//                   fully folded (chunk-renormalized scale), fp32, 2 x 1 MB.
//                   Removes all sincosf/exp2f/log2f from proj's epilogue.
// ---------------------------------------------------------------------------
__global__ __launch_bounds__(256) void prep_w(
    const float* __restrict__ WQ, const float* __restrict__ WK,
    const float* __restrict__ WV, _Float16* __restrict__ Wf,
    float2* __restrict__ tabQ, float2* __restrict__ tabK)
{
    const unsigned tid = threadIdx.x;
    if (blockIdx.x < 96) {
        const unsigned t = blockIdx.x * 256 + tid;   // 0..24575
        const unsigned kchunk = t / 1536u;
        const unsigned s = t - kchunk * 1536u;
        const int ct2  = s >> 6;            // (n16)*2 + kt
        const int lane = s & 63;
        const int n16  = ct2 >> 1;
        const int kt   = ct2 & 1;
        const int quad = lane >> 4;
        const int n    = n16 * 16 + (lane & 15);
        const int k0   = (int)kchunk * 64 + kt * 32 + quad * 8;
        const int m    = n >> 6;
        const int d    = n & 63;
        const float* Wm = (m == 0) ? WQ : (m == 1) ? WK : WV;
        f16x8 hv;
#pragma unroll
        for (int j = 0; j < 8; ++j)
            hv[j] = (_Float16)(Wm[(size_t)(k0 + j) * DD + d] * 1024.f);
        *(f16x8*)&Wf[(size_t)t * 8] = hv;
    } else {
        const unsigned t2 = (blockIdx.x - 96) * 256 + tid;  // 0..131071
        const int i2  = (int)(t2 >> 12);            // freq index 0..31
        const int pos = (int)(t2 & 4095u);          // abs position
        const float ifr = exp2f(-13.28771237954945f * ((float)i2 / 32.f));
        float sn, cn;
        sincosf((float)pos * ifr, &sn, &cn);
        const float sv   = (2.f * (float)i2 + 25.6f) / 89.6f;
        const float l2sv = log2f(sv);
        const float arg  = ((float)(pos & 63) * (1.f / 512.f)) * l2sv;
        const float sq = exp2f(arg);                // Q scale (renorm by chunk)
        const float sk = exp2f(-arg);               // K downscale
        tabQ[t2] = make_float2(cn * sq, sn * sq);
        tabK[t2] = make_float2(cn * sk, sn * sk);
    }
}

// ---------------------------------------------------------------------------
// Kernel 1: MFMA projection. 32 rows/block (grid 256), 256 thr (4 waves),
// BARRIER-FREE, ZERO LDS. Wave w owns coltiles 3w..3w+2 and BOTH 16-row
// sets -> each B-frag load feeds 2 MFMAs => aggregate Wf L2 traffic halves
// (201 MB -> 100 MB). Register double-buffer on the K-chunk loop.
// Epilogue: table-driven xPos (2 float4 loads per coltile, no sincosf).
// Outputs unchanged: Qr row-major fp16; Kf frag slabs; Vf frag cells.
// ---------------------------------------------------------------------------
__global__ __launch_bounds__(256) void proj_mfma(
    const float* __restrict__ X, const _Float16* __restrict__ Wf,
    const float2* __restrict__ tabQ, const float2* __restrict__ tabK,
    _Float16* __restrict__ Qr, _Float16* __restrict__ Kf,
    _Float16* __restrict__ Vf)
{
    const int tid  = threadIdx.x;
    const int wv   = tid >> 6;
    const int lane = tid & 63;
    const int quad = lane >> 4;
    const int l15  = lane & 15;
    const int rg   = blockIdx.x;                 // 0..255, 32 rows each
    const size_t xrow0 = (size_t)(rg * 32 + l15) * HH;
    const size_t xrow1 = xrow0 + (size_t)16 * HH;

    f32x4 acc[2][3];
#pragma unroll
    for (int s = 0; s < 2; ++s)
#pragma unroll
        for (int i = 0; i < 3; ++i) acc[s][i] = (f32x4){0.f, 0.f, 0.f, 0.f};

    float4 pA[2][4];       // [rowset][kt*2+half]: k = kt*32 + quad*8 + (0..7)
    f16x8  pB[6];          // [cj*2+kt]
    {   // prefetch chunk 0
        const float* xp0 = &X[xrow0 + quad * 8];
        const float* xp1 = &X[xrow1 + quad * 8];
        pA[0][0] = *(const float4*)&xp0[0];
        pA[0][1] = *(const float4*)&xp0[4];
        pA[0][2] = *(const float4*)&xp0[32];
        pA[0][3] = *(const float4*)&xp0[36];
        pA[1][0] = *(const float4*)&xp1[0];
        pA[1][1] = *(const float4*)&xp1[4];
        pA[1][2] = *(const float4*)&xp1[32];
        pA[1][3] = *(const float4*)&xp1[36];
#pragma unroll
        for (int cj = 0; cj < 3; ++cj)
#pragma unroll
            for (int kt = 0; kt < 2; ++kt)
                pB[cj * 2 + kt] = *(const f16x8*)&Wf[
                    (size_t)((((wv * 3 + cj) * 2 + kt) * 64 + lane)) * 8];
    }

    for (int ch = 0; ch < 16; ++ch) {
        // convert A to fp16 frags (both row sets)
        f16x8 a[2][2];
#pragma unroll
        for (int s = 0; s < 2; ++s)
#pragma unroll
            for (int kt = 0; kt < 2; ++kt) {
                const float4 xa = pA[s][kt * 2], xb = pA[s][kt * 2 + 1];
                a[s][kt][0] = (_Float16)xa.x; a[s][kt][1] = (_Float16)xa.y;
                a[s][kt][2] = (_Float16)xa.z; a[s][kt][3] = (_Float16)xa.w;
                a[s][kt][4] = (_Float16)xb.x; a[s][kt][5] = (_Float16)xb.y;
                a[s][kt][6] = (_Float16)xb.z; a[s][kt][7] = (_Float16)xb.w;
            }
        f16x8 b[6];
#pragma unroll
        for (int i = 0; i < 6; ++i) b[i] = pB[i];

        if (ch + 1 < 16) {   // prefetch next chunk (overlaps MFMAs)
            const float* xp0 = &X[xrow0 + (ch + 1) * 64 + quad * 8];
            const float* xp1 = &X[xrow1 + (ch + 1) * 64 + quad * 8];
            pA[0][0] = *(const float4*)&xp0[0];
            pA[0][1] = *(const float4*)&xp0[4];
            pA[0][2] = *(const float4*)&xp0[32];
            pA[0][3] = *(const float4*)&xp0[36];
            pA[1][0] = *(const float4*)&xp1[0];
            pA[1][1] = *(const float4*)&xp1[4];
            pA[1][2] = *(const float4*)&xp1[32];
            pA[1][3] = *(const float4*)&xp1[36];
            const size_t cb = (size_t)(ch + 1) * WCH;
#pragma unroll
            for (int cj = 0; cj < 3; ++cj)
#pragma unroll
                for (int kt = 0; kt < 2; ++kt)
                    pB[cj * 2 + kt] = *(const f16x8*)&Wf[cb +
                        (size_t)((((wv * 3 + cj) * 2 + kt) * 64 + lane)) * 8];
        }
#pragma unroll
        for (int kt = 0; kt < 2; ++kt)
#pragma unroll
            for (int cj = 0; cj < 3; ++cj)
#pragma unroll
                for (int s = 0; s < 2; ++s)
                    acc[s][cj] = __builtin_amdgcn_mfma_f32_16x16x32_f16(
                        a[s][kt], b[cj * 2 + kt], acc[s][cj], 0, 0, 0);
    }

    // ---- epilogue: descale + table-driven xPos ----
#pragma unroll
    for (int s = 0; s < 2; ++s) {
        const int rowq = rg * 32 + s * 16 + quad * 4;  // quad's base row
#pragma unroll
        for (int cj = 0; cj < 3; ++cj) {
            const int ctg = wv * 3 + cj;
            const f32x4 v = acc[s][cj];
            const int col = ctg * 16 + l15;
            const int mat = ctg >> 2;            // 0=Q 1=K 2=V
            const int d   = col & 63;
            if (mat < 2) {
                const int i2 = d >> 1;
                const float2* tab = (mat == 0) ? tabQ : tabK;
                const float2* tp = tab + ((size_t)i2 << 12) + (rowq & (LL - 1));
                const float4 cs01 = *(const float4*)tp;        // (c0,s0,c1,s1)
                const float4 cs23 = *(const float4*)(tp + 2);  // (c2,s2,c3,s3)
#pragma unroll
                for (int r = 0; r < 4; ++r) {
                    const int row = rowq + r;
                    const float val = v[r] * (1.f / 1024.f);
                    const float p = __shfl_xor(val, 1, 64);
                    const float cc = (r == 0) ? cs01.x : (r == 1) ? cs01.z
                                   : (r == 2) ? cs23.x : cs23.z;
                    const float ss = (r == 0) ? cs01.y : (r == 1) ? cs01.w
                                   : (r == 2) ? cs23.y : cs23.w;
                    const float o = ((col & 1) == 0) ? val * cc - p * ss
                                                     : val * cc + p * ss;
                    if (mat == 0) {
                        Qr[(size_t)row * DD + d] = (_Float16)o;
                    } else {
                        const int b2 = row >> 12, posb = row & 4095;
                        Kf[(((size_t)b2 * 8 + (d >> 3)) * 4096 + posb) * 8 + (d & 7)] =
                            (_Float16)o;
                    }
                }
            } else {
                f16x4 vv;
#pragma unroll
                for (int r = 0; r < 4; ++r) vv[r] = (_Float16)(v[r] * (1.f / 1024.f));
                const int b2 = rowq >> 12, posb = rowq & 4095;
                *(f16x4*)&Vf[(((size_t)b2 * 512 + (posb >> 3)) * 64 + d) * 8 + (posb & 7)] = vv;
            }
        }
    }
}

// ---------------------------------------------------------------------------
// Kernel 2: chunk output, direct cross-attention over prev 8 chunks.
// grid 512 = (chunk 128) x (row-quarter 4), 256 thr, 4 waves.
// Phase B fully unrolled + branchless address select so the compiler can
// software-pipeline the 36 independent L2 loads across the MFMA chain.
// ---------------------------------------------------------------------------
__global__ __launch_bounds__(256) void chunk_out(
    const _Float16* __restrict__ Qr, const _Float16* __restrict__ Kf,
    const _Float16* __restrict__ Vf, float* __restrict__ out)
{
    __shared__ __align__(16) unsigned char smraw[20032];
    _Float16* Sb  = (_Float16*)smraw;             // 16 x SBS f16 = 18688 B
    _Float16* svp = (_Float16*)(smraw + 18688);   // 512 f16 = 1024 B
    float*    pwl = (float*)(smraw + 19712);      // 65 f32

    const int tid   = threadIdx.x;
    const int bc    = blockIdx.x;
    const int chunk = bc >> 2;
    const int qt    = bc & 3;
    const int w     = tid >> 6;
    const int lane  = tid & 63;
    const int quad  = lane >> 4;
    const int l15   = lane & 15;
    const int cloc  = chunk & 63;
    const int bB    = chunk >> 6;
    const size_t rowbase = (size_t)chunk * CHK + qt * 16;
    const float l2g = log2f(GAMMA);

    if (tid < 65) pwl[tid] = exp2f((float)tid * l2g);
#pragma unroll
    for (int e = 0; e < 2; ++e) {     // svp[(D-1)*64 + d] = sv_d^(D/8)
        const int idx = tid + e * 256;
        const int dl  = (idx >> 6) + 1;
        const int dd  = idx & 63;
        const float sv = (2.f * (float)(dd >> 1) + 25.6f) / 89.6f;
        svp[idx] = (_Float16)exp2f(0.125f * (float)dl * log2f(sv));
    }

    // A-frags (block's 16 Q rows; same for all waves)
    f16x8 aQ[2];
#pragma unroll
    for (int ks = 0; ks < 2; ++ks)
        aQ[ks] = *(const f16x8*)&Qr[(rowbase + l15) * DD + ks * 32 + quad * 8];
    __syncthreads();   // svp, pwl ready

    // ---- phase A intra (wave w: m = w*16..w*16+15) ----
    {
        const int posb = cloc * 64 + w * 16 + l15;
        f32x4 sA = (f32x4){0.f, 0.f, 0.f, 0.f};
#pragma unroll
        for (int ks = 0; ks < 2; ++ks) {
            const f16x8 bK = *(const f16x8*)&Kf[(((size_t)bB * 8 + ks * 4 + quad)
                                                * 4096 + posb) * 8];
            sA = __builtin_amdgcn_mfma_f32_16x16x32_f16(aQ[ks], bK, sA, 0, 0, 0);
        }
        const int m = w * 16 + l15;
#pragma unroll
        for (int r = 0; r < 4; ++r) {
            const int nl = quad * 4 + r;
            const int n64 = qt * 16 + nl;
            const float val = (n64 >= m) ? sA[r] * pwl[n64 - m] : 0.f;
            Sb[nl * SBS + m] = (_Float16)val;
        }
    }

    // ---- phase A cross: 8 jtiles/wave over prev 512 keys ----
    for (int jc = w; jc < 32; jc += 4) {
        const int dlt = 8 - (jc >> 2);                 // chunk distance 1..8
        const bool valid = (dlt <= cloc);
        const int mq = (jc * 16 + l15) & 63;
        const float gl = valid ? exp2f((float)(64 * dlt - mq) * l2g) : 0.f;
        const _Float16 glh = (_Float16)gl;
        const int cs = valid ? (chunk - dlt) : chunk;
        const int posb = (cs & 63) * 64 + mq;
        f32x4 sc4 = (f32x4){0.f, 0.f, 0.f, 0.f};
#pragma unroll
        for (int ks = 0; ks < 2; ++ks) {
            const f16x8 bk = *(const f16x8*)&Kf[(((size_t)bB * 8 + ks * 4 + quad)
                                                * 4096 + posb) * 8];
            const f16x8 sv8 = *(const f16x8*)&svp[(dlt - 1) * 64 + ks * 32 + quad * 8];
            f16x8 b2;
#pragma unroll
            for (int j = 0; j < 8; ++j) b2[j] = bk[j] * glh * sv8[j];
            sc4 = __builtin_amdgcn_mfma_f32_16x16x32_f16(aQ[ks], b2, sc4, 0, 0, 0);
        }
#pragma unroll
        for (int r = 0; r < 4; ++r) {
            const int nl = quad * 4 + r;
            const int na = qt * 16 + nl;
            Sb[nl * SBS + 64 + jc * 16 + l15] = (_Float16)(sc4[r] * pwl[na]);
        }
    }
    __syncthreads();

    // ---- phase B: out = S @ V_all (576 k); wave w: d' = w*16..+15 ----
    f32x4 oA = (f32x4){0.f, 0.f, 0.f, 0.f};
    const int dp = w * 16 + l15;
    const int chunkbase = chunk & ~63;
#pragma unroll
    for (int ks5 = 0; ks5 < 18; ++ks5) {
        const f16x8 aS = *(const f16x8*)&Sb[l15 * SBS + ks5 * 32 + quad * 8];
        const int m0 = ks5 * 32 + quad * 8;
        int gr;
        if (ks5 < 2) {
            gr = chunk * 64 + m0;
        } else {
            const int mc = m0 - 64;
            int cs2 = chunk - 8 + (mc >> 6);
            cs2 = (cs2 < chunkbase) ? chunk : cs2;     // invalid -> S cols are 0
            gr = cs2 * 64 + (mc & 63);
        }
        const int b2 = gr >> 12, pb = gr & 4095;
        const size_t vb = ((size_t)b2 * 512 + (pb >> 3)) * 64;
        const f16x8 bV = *(const f16x8*)&Vf[(vb + dp) * 8];
        oA = __builtin_amdgcn_mfma_f32_16x16x32_f16(aS, bV, oA, 0, 0, 0);
    }
#pragma unroll
    for (int r = 0; r < 4; ++r)
        out[(rowbase + quad * 4 + r) * DD + dp] = oA[r];
}

// ---------------------------------------------------------------------------
extern "C" void kernel_launch(void* const* d_in, const int* in_sizes, int n_in,
                              void* d_out, int out_size, void* d_ws, size_t ws_size,
                              hipStream_t stream)
{
    const float* X  = (const float*)d_in[0];
    const float* WQ = (const float*)d_in[1];
    const float* WK = (const float*)d_in[2];
    const float* WV = (const float*)d_in[3];
    float* outp = (float*)d_out;

    _Float16* Wf = (_Float16*)d_ws;                  // 196608 h
    _Float16* Qr = Wf + 196608;                      // 524288 h
    _Float16* Kf = Qr + (size_t)BLROWS * DD;         // 524288 h
    _Float16* Vf = Kf + (size_t)BLROWS * DD;         // 524288 h
    float2* tabQ = (float2*)(Vf + (size_t)BLROWS * DD);  // 131072 float2 = 1 MB
    float2* tabK = tabQ + 131072;                        // 1 MB
    // total ~5.5 MB

    hipLaunchKernelGGL(prep_w, dim3(608), dim3(256), 0, stream,
                       WQ, WK, WV, Wf, tabQ, tabK);
    hipLaunchKernelGGL(proj_mfma, dim3(256), dim3(256), 0, stream,
                       X, Wf, tabQ, tabK, Qr, Kf, Vf);
    hipLaunchKernelGGL(chunk_out, dim3(512), dim3(256), 0, stream,
                       Qr, Kf, Vf, outp);
}